// Round 1
// baseline (111.643 us; speedup 1.0000x reference)
//
#include <hip/hip_runtime.h>
#include <math.h>

// FrequencyMaskingLoss — psychoacoustic masking loss (forward only, scalar out).
// Pipeline (3 launches):
//   [K0] <<<3,256>>>  constant tables (f64 math), block-specialized; init acc/ticket
//   [K1] <<<nf,256>>> STFT(ref & delta via one complex FFT) + per-frame PSD + frame max
//        - float2 ping-pong FFT, ONE barrier per stage (9 vs 18)
//        - LDS index swizzle i+(i>>4) kills stride-2^k bank conflicts
//   [K3] <<<nf,256>>> global max (redundant per-block reduce of fmaxs, bitwise
//        identical) + masking threshold + loss partial + atomic final sum; last
//        block (ticket) writes out[0].
// WINDOW=512, HOP=128, F=257, n_frames=(L-512)/128+1 (=1247 for L=160000).

#define FBINS 257

// table layout inside ws (floats): barkf[257] | athdb[257] | athp[257] |
//                                  hann[512] | twr[256] | twi[256]   (= 1795)
#define TAB_BARK  0
#define TAB_ATHDB 257
#define TAB_ATHP  514
#define TAB_HANN  771
#define TAB_TWR   1283
#define TAB_TWI   1539
#define TAB_FLOATS 2048   // padded

// LDS bank-conflict-avoiding index swizzle (pad 1 slot every 16). Injective,
// monotone; max swz(511)=542.
__device__ __forceinline__ int swz(int i) { return i + (i >> 4); }

// ---------------------------------------------------------------- kernel 0
// 3 blocks on 3 CUs: block0 = freq tables (+acc/ticket init), block1 = hann,
// block2 = twiddles. All double-precision table math lives here.
__global__ __launch_bounds__(256) void k0_init(
    float* __restrict__ tab, float* __restrict__ acc, unsigned int* __restrict__ ticket)
{
    const int tid = threadIdx.x;
    const double TWO_PI = 6.283185307179586476925286766559;
    if (blockIdx.x == 0) {
        if (tid == 0) { acc[0] = 0.0f; ticket[0] = 0u; }
        for (int f = tid; f < FBINS; f += 256) {
            double freq = 31.25 * (double)f;            // SR/2/256 * f, exact
            double q    = freq / 7500.0;
            tab[TAB_BARK + f] = (float)(13.0 * atan(0.00076 * freq) + 3.5 * atan(q * q));
            if (f == 0) {
                tab[TAB_ATHDB] = -INFINITY;
                tab[TAB_ATHP]  = 0.0f;
            } else {
                double fk = freq * 0.001;
                double ad = 3.64 * pow(fk, -0.8)
                          - 6.5 * exp(-0.6 * (fk - 3.3) * (fk - 3.3))
                          + 0.001 * fk * fk * fk * fk - 12.0;
                float av = (float)ad;
                tab[TAB_ATHDB + f] = av;
                tab[TAB_ATHP  + f] = exp10f(av / 10.0f);
            }
        }
    } else if (blockIdx.x == 1) {
        for (int n = tid; n < 512; n += 256) {
            double cw = cos((TWO_PI * (double)n) / 512.0);
            tab[TAB_HANN + n] = (float)(0.5 * (1.0 - cw));
        }
    } else {
        for (int j = tid; j < 256; j += 256) {
            double s, c;
            sincos(-(TWO_PI / 512.0) * (double)j, &s, &c);
            tab[TAB_TWR + j] = (float)c;
            tab[TAB_TWI + j] = (float)s;
        }
    }
}

// ---------------------------------------------------------------- kernel 1
// One frame per block; z = hann*ref + i*hann*delta -> one 512-pt complex FFT.
// Ping-pong buffers: one __syncthreads per stage. Same op order as the
// original radix-2 DIT -> bitwise-identical spectra.
__global__ __launch_bounds__(256) void k1_stft(
    const float* __restrict__ xadv, const float* __restrict__ xref,
    const float* __restrict__ tab,
    float* __restrict__ psd_db, float* __restrict__ pd, float* __restrict__ fmaxs)
{
    __shared__ float2 z[2][544];    // 512 + swizzle padding
    __shared__ float2 tw[272];      // 256 + swizzle padding
    __shared__ float wmax[4];
    const int t = blockIdx.x, tid = threadIdx.x;

    tw[swz(tid)] = make_float2(tab[TAB_TWR + tid], tab[TAB_TWI + tid]);

    const int base_idx = t * 128;
    for (int n = tid; n < 512; n += 256) {
        float w = tab[TAB_HANN + n];
        float r = xref[base_idx + n];
        float a = xadv[base_idx + n];
        int   p = __brev((unsigned)n) >> 23;   // 9-bit reversal
        z[0][swz(p)] = make_float2(w * r, w * (a - r));
    }
    __syncthreads();

    // 9-stage radix-2 DIT, one butterfly per thread per stage, ping-pong
    int cur = 0;
    for (int stage = 1; stage <= 9; ++stage) {
        int half  = 1 << (stage - 1);
        int tstep = 512 >> stage;
        int j     = tid & (half - 1);
        int base  = ((tid >> (stage - 1)) << stage) + j;
        float2 w  = tw[swz(j * tstep)];
        float2 u  = z[cur][swz(base)];
        float2 v  = z[cur][swz(base + half)];
        float vr = v.x * w.x - v.y * w.y;
        float vi = v.x * w.y + v.y * w.x;
        z[cur ^ 1][swz(base)]        = make_float2(u.x + vr, u.y + vi);
        z[cur ^ 1][swz(base + half)] = make_float2(u.x - vr, u.y - vi);
        cur ^= 1;
        __syncthreads();
    }
    // data now in z[cur]

    // unpack A=rfft(ref), B=rfft(delta); PSDs
    const float S2 = 1.0172526041666667e-05f;   // (sqrt(8/3)/512)^2
    float lmax = -1e30f;
    for (int k = tid; k <= 256; k += 256) {
        int nk = (512 - k) & 511;
        float2 zk = z[cur][swz(k)];
        float2 zn = z[cur][swz(nk)];
        float ar = 0.5f * (zk.x + zn.x), ai = 0.5f * (zk.y - zn.y);   // ref spectrum
        float br = 0.5f * (zk.y + zn.y), bi = 0.5f * (zn.x - zk.x);   // delta spectrum
        float prefp = S2 * (ar * ar + ai * ai);
        float pdb   = fmaxf(10.0f * log10f(prefp), -200.0f);
        psd_db[t * FBINS + k] = pdb;
        pd[t * FBINS + k]     = S2 * (br * br + bi * bi);
        lmax = fmaxf(lmax, pdb);
    }
    for (int off = 32; off > 0; off >>= 1) lmax = fmaxf(lmax, __shfl_down(lmax, off));
    if ((tid & 63) == 0) wmax[tid >> 6] = lmax;
    __syncthreads();
    if (tid == 0)
        fmaxs[t] = fmaxf(fmaxf(wmax[0], wmax[1]), fmaxf(wmax[2], wmax[3]));
}

// ---------------------------------------------------------------- kernel 3
// Fuses old k2 (global max: every block reduces fmaxs identically -> bitwise
// same pmax) and old k4 (atomicAdd accumulator + ticket; last block writes out).
__global__ __launch_bounds__(256) void k3_threshold(
    const float* __restrict__ tab,
    const float* __restrict__ psd_db, const float* __restrict__ pd,
    const float* __restrict__ fmaxs, int nf,
    float* __restrict__ acc, unsigned int* __restrict__ ticket,
    float* __restrict__ out)
{
    __shared__ float barkf[FBINS], athp_s[FBINS];
    __shared__ float p_s[FBINS], pw_s[FBINS];
    __shared__ float mc_s[128], shift_s[128], barkm_s[128], ups_s[128];
    __shared__ int   bin_s[128], keep_s[128];
    __shared__ int   wcnt[4];
    __shared__ float red[4];
    __shared__ float smax[4];

    const int t = blockIdx.x, tid = threadIdx.x;
    const int lane = tid & 63, wid = tid >> 6;

    // tables into LDS (pmax-independent) + global-max reduce of fmaxs
    for (int f = tid; f < FBINS; f += 256) {
        barkf[f]  = tab[TAB_BARK + f];
        athp_s[f] = tab[TAB_ATHP + f];
    }
    float v = -1e30f;
    for (int i = tid; i < nf; i += 256) v = fmaxf(v, fmaxs[i]);
    for (int off = 32; off > 0; off >>= 1) v = fmaxf(v, __shfl_down(v, off));
    if (lane == 0) smax[wid] = v;
    __syncthreads();
    const float pmax   = fmaxf(fmaxf(smax[0], smax[1]), fmaxf(smax[2], smax[3]));
    const float shift0 = 96.0f - pmax;

    for (int f = tid; f < FBINS; f += 256) {
        float pv = shift0 + psd_db[t * FBINS + f];
        p_s[f]  = pv;
        pw_s[f] = exp10f(pv / 10.0f);
    }
    __syncthreads();

    // local-max + tonal masker level for f = tid (bin 256 can't be interior)
    float m = -1e30f;
    int   pred = 0;
    if (tid >= 1 && tid <= 255) {
        float pc = p_s[tid];
        if (pc > p_s[tid - 1] && pc > p_s[tid + 1]) {
            m = 10.0f * log10f((pw_s[tid] + pw_s[tid - 1]) + pw_s[tid + 1]);
            if (m > tab[TAB_ATHDB + tid]) pred = 1;
        }
    }
    // ballot stream-compaction (stable in frequency order)
    unsigned long long bal = __ballot(pred);
    if (lane == 0) wcnt[wid] = __popcll(bal);
    __syncthreads();
    int base = 0;
    for (int w = 0; w < wid; ++w) base += wcnt[w];
    const int n_total = wcnt[0] + wcnt[1] + wcnt[2] + wcnt[3];
    if (pred) {
        int pos = base + __popcll(bal & ((1ull << lane) - 1));
        bin_s[pos] = tid; mc_s[pos] = m; keep_s[pos] = 1;
    }
    __syncthreads();

    // the inherently-sequential i_prev scan (faithful incl. position-indexed
    // BARK[] access): thread 0, ~n_total iterations
    if (tid == 0) {
        int i_prev = 0;
        for (int i = 1; i < n_total; ++i) {
            bool close        = (barkf[i] - barkf[i_prev]) < 0.5f;  // positions!
            bool prev_smaller = mc_s[i_prev] < mc_s[i];
            if (close) {
                keep_s[prev_smaller ? i_prev : i] = 0;
                if (prev_smaller) i_prev = i_prev + 1;
            } else {
                i_prev = i;
            }
        }
    }
    __syncthreads();

    // compact kept maskers (ballot again), precompute per-masker terms
    int pred2 = (tid < n_total) && keep_s[tid];
    unsigned long long bal2 = __ballot(pred2);
    if (lane == 0) wcnt[wid] = __popcll(bal2);
    __syncthreads();
    int base2 = 0;
    for (int w = 0; w < wid; ++w) base2 += wcnt[w];
    const int nk = wcnt[0] + wcnt[1] + wcnt[2] + wcnt[3];
    if (pred2) {
        int pos = base2 + __popcll(bal2 & ((1ull << lane) - 1));
        int   fb = bin_s[tid];
        float mc = mc_s[tid];
        shift_s[pos] = mc + (-6.025f - 0.275f * barkf[fb]);
        barkm_s[pos] = barkf[fb];
        ups_s[pos]   = -27.0f + 0.37f * fmaxf(mc - 40.0f, 0.0f);
    }
    __syncthreads();

    // per-bin threshold power + loss (threshold kept in POWER domain:
    // 10^(10*log10(X)/10) == X — skip the log/exp round-trip)
    const float C = 3981071705.534973f / exp10f(pmax / 10.0f);  // 10^9.6/10^(pmax/10)
    float lsum = 0.0f;
    for (int f = tid; f < FBINS; f += 256) {
        float bf  = barkf[f];
        float acc2 = 0.0f;
        for (int k = 0; k < nk; ++k) {
            float dz    = bf - barkm_s[k];
            float slope = (dz > 0.0f) ? ups_s[k] : 27.0f;
            float tdb   = shift_s[k] + slope * dz;
            acc2 += exp10f(tdb / 10.0f);
        }
        float thrpow = acc2 + athp_s[f];
        float pds    = C * pd[t * FBINS + f];
        lsum += fmaxf(pds - thrpow, 0.0f);
    }
    for (int off = 32; off > 0; off >>= 1) lsum += __shfl_down(lsum, off);
    if ((tid & 63) == 0) red[tid >> 6] = lsum;
    __syncthreads();

    // fused finalization: device-coherent atomic accumulate + ticket;
    // the last block to arrive reads the final sum (atomic RMW -> coherent
    // across XCDs) and writes the scalar output.
    if (tid == 0) {
        float total = (red[0] + red[1]) + (red[2] + red[3]);
        atomicAdd(acc, total);
        __threadfence();
        unsigned int old = atomicAdd(ticket, 1u);
        if (old == (unsigned int)(nf - 1)) {
            float tot = atomicAdd(acc, 0.0f);   // returns value before add = final sum
            out[0] = 1e-6f * (tot / (float)(nf * FBINS));
        }
    }
}

// ---------------------------------------------------------------- launch
extern "C" void kernel_launch(void* const* d_in, const int* in_sizes, int n_in,
                              void* d_out, int out_size, void* d_ws, size_t ws_size,
                              hipStream_t stream)
{
    const float* x_adv = (const float*)d_in[0];
    const float* x_ref = (const float*)d_in[1];
    float*       out   = (float*)d_out;

    const int L  = in_sizes[0];
    const int nf = (L - 512) / 128 + 1;           // 1247 for L=160000

    // workspace layout (floats)
    float* ws      = (float*)d_ws;
    float* tab     = ws;                                   // TAB_FLOATS
    float* psd_db  = ws + TAB_FLOATS;                      // nf*257
    float* pd      = psd_db + (size_t)nf * FBINS;          // nf*257
    float* fmaxs   = pd + (size_t)nf * FBINS;              // nf
    float* acc     = fmaxs + nf;                           // 1
    unsigned int* ticket = (unsigned int*)(acc + 1);       // 1

    k0_init     <<<3,  256, 0, stream>>>(tab, acc, ticket);
    k1_stft     <<<nf, 256, 0, stream>>>(x_adv, x_ref, tab, psd_db, pd, fmaxs);
    k3_threshold<<<nf, 256, 0, stream>>>(tab, psd_db, pd, fmaxs, nf, acc, ticket, out);
}

// Round 2
// 89.253 us; speedup vs baseline: 1.2509x; 1.2509x over previous
//
#include <hip/hip_runtime.h>
#include <math.h>

// FrequencyMaskingLoss — psychoacoustic masking loss (forward only, scalar out).
// Pipeline: [K0] init constant tables (f64 math, 3 specialized blocks)
//           [K1] STFT(ref & delta via one complex FFT) + per-frame PSD + frame max
//                - scalar re/im ping-pong FFT: 9 barriers (was 18), same bank
//                  pattern as the proven round-0 kernel (stride-2 float = free)
//           [K2] global psd_max   [K3] per-frame masking threshold + loss partial
//                - serial i_prev scan software-pipelined: packed float2
//                  (bark,mc) pairs + register state + 1-iter prefetch
//           [K4] mean -> out[0]
// WINDOW=512, HOP=128, F=257, n_frames=(L-512)/128+1 (=1247 for L=160000).

#define FBINS 257

// table layout inside ws (floats): barkf[257] | athdb[257] | athp[257] |
//                                  hann[512] | twr[256] | twi[256]   (= 1795)
#define TAB_BARK  0
#define TAB_ATHDB 257
#define TAB_ATHP  514
#define TAB_HANN  771
#define TAB_TWR   1283
#define TAB_TWI   1539
#define TAB_FLOATS 2048   // padded

// ---------------------------------------------------------------- kernel 0
// 3 blocks on 3 CUs: block0 = freq tables, block1 = hann, block2 = twiddles.
// All double-precision table math lives here (frame-invariant).
__global__ __launch_bounds__(256) void k0_init(float* __restrict__ tab)
{
    const int tid = threadIdx.x;
    const double TWO_PI = 6.283185307179586476925286766559;
    if (blockIdx.x == 0) {
        for (int f = tid; f < FBINS; f += 256) {
            double freq = 31.25 * (double)f;            // SR/2/256 * f, exact
            double q    = freq / 7500.0;
            tab[TAB_BARK + f] = (float)(13.0 * atan(0.00076 * freq) + 3.5 * atan(q * q));
            if (f == 0) {
                tab[TAB_ATHDB] = -INFINITY;
                tab[TAB_ATHP]  = 0.0f;
            } else {
                double fk = freq * 0.001;
                double ad = 3.64 * pow(fk, -0.8)
                          - 6.5 * exp(-0.6 * (fk - 3.3) * (fk - 3.3))
                          + 0.001 * fk * fk * fk * fk - 12.0;
                float av = (float)ad;
                tab[TAB_ATHDB + f] = av;
                tab[TAB_ATHP  + f] = exp10f(av / 10.0f);
            }
        }
    } else if (blockIdx.x == 1) {
        for (int n = tid; n < 512; n += 256) {
            double cw = cos((TWO_PI * (double)n) / 512.0);
            tab[TAB_HANN + n] = (float)(0.5 * (1.0 - cw));
        }
    } else {
        for (int j = tid; j < 256; j += 256) {
            double s, c;
            sincos(-(TWO_PI / 512.0) * (double)j, &s, &c);
            tab[TAB_TWR + j] = (float)c;
            tab[TAB_TWI + j] = (float)s;
        }
    }
}

// ---------------------------------------------------------------- kernel 1
// One frame per block; z = hann*ref + i*hann*delta -> one 512-pt complex FFT.
// Scalar re/im ping-pong: ONE barrier per stage, identical arithmetic order
// and identical LDS bank pattern (stride-2 float = 2-way = free) to round 0.
__global__ __launch_bounds__(256) void k1_stft(
    const float* __restrict__ xadv, const float* __restrict__ xref,
    const float* __restrict__ tab,
    float* __restrict__ psd_db, float* __restrict__ pd, float* __restrict__ fmaxs)
{
    __shared__ float re[2][512], im[2][512], twr[256], twi[256];
    __shared__ float wmax[4];
    const int t = blockIdx.x, tid = threadIdx.x;

    twr[tid] = tab[TAB_TWR + tid];
    twi[tid] = tab[TAB_TWI + tid];

    const int base_idx = t * 128;
    for (int n = tid; n < 512; n += 256) {
        float w = tab[TAB_HANN + n];
        float r = xref[base_idx + n];
        float a = xadv[base_idx + n];
        int   p = __brev((unsigned)n) >> 23;   // 9-bit reversal
        re[0][p] = w * r;
        im[0][p] = w * (a - r);
    }
    __syncthreads();

    // 9-stage radix-2 DIT, one butterfly per thread per stage, ping-pong
    int cur = 0;
    for (int stage = 1; stage <= 9; ++stage) {
        int half  = 1 << (stage - 1);
        int tstep = 512 >> stage;
        int j     = tid & (half - 1);
        int base  = ((tid >> (stage - 1)) << stage) + j;
        float wr = twr[j * tstep], wi = twi[j * tstep];
        float vr0 = re[cur][base + half], vi0 = im[cur][base + half];
        float vr = vr0 * wr - vi0 * wi;
        float vi = vr0 * wi + vi0 * wr;
        float ur = re[cur][base], ui = im[cur][base];
        re[cur ^ 1][base]        = ur + vr; im[cur ^ 1][base]        = ui + vi;
        re[cur ^ 1][base + half] = ur - vr; im[cur ^ 1][base + half] = ui - vi;
        cur ^= 1;
        __syncthreads();
    }
    // data now in re[cur]/im[cur] (cur == 1 after 9 stages)

    // unpack A=rfft(ref), B=rfft(delta); PSDs
    const float S2 = 1.0172526041666667e-05f;   // (sqrt(8/3)/512)^2
    float lmax = -1e30f;
    for (int k = tid; k <= 256; k += 256) {
        int nk = (512 - k) & 511;
        float zr = re[cur][k],  zi = im[cur][k];
        float yr = re[cur][nk], yi = im[cur][nk];
        float ar = 0.5f * (zr + yr), ai = 0.5f * (zi - yi);   // ref spectrum
        float br = 0.5f * (zi + yi), bi = 0.5f * (yr - zr);   // delta spectrum
        float prefp = S2 * (ar * ar + ai * ai);
        float pdb   = fmaxf(10.0f * log10f(prefp), -200.0f);
        psd_db[t * FBINS + k] = pdb;
        pd[t * FBINS + k]     = S2 * (br * br + bi * bi);
        lmax = fmaxf(lmax, pdb);
    }
    for (int off = 32; off > 0; off >>= 1) lmax = fmaxf(lmax, __shfl_down(lmax, off));
    if ((tid & 63) == 0) wmax[tid >> 6] = lmax;
    __syncthreads();
    if (tid == 0)
        fmaxs[t] = fmaxf(fmaxf(wmax[0], wmax[1]), fmaxf(wmax[2], wmax[3]));
}

// ---------------------------------------------------------------- kernel 2
__global__ __launch_bounds__(256) void k2_max(
    const float* __restrict__ fmaxs, int nf, float* __restrict__ psdmax)
{
    __shared__ float sm[4];
    float v = -1e30f;
    for (int i = threadIdx.x; i < nf; i += 256) v = fmaxf(v, fmaxs[i]);
    for (int off = 32; off > 0; off >>= 1) v = fmaxf(v, __shfl_down(v, off));
    if ((threadIdx.x & 63) == 0) sm[threadIdx.x >> 6] = v;
    __syncthreads();
    if (threadIdx.x == 0)
        psdmax[0] = fmaxf(fmaxf(sm[0], sm[1]), fmaxf(sm[2], sm[3]));
}

// ---------------------------------------------------------------- kernel 3
__global__ __launch_bounds__(256) void k3_threshold(
    const float* __restrict__ tab,
    const float* __restrict__ psd_db, const float* __restrict__ pd,
    const float* __restrict__ psdmax, float* __restrict__ floss)
{
    __shared__ float barkf[FBINS], athp_s[FBINS];
    __shared__ float p_s[FBINS], pw_s[FBINS];
    __shared__ float mc_s[128], shift_s[128], barkm_s[128], ups_s[128];
    __shared__ int   bin_s[128], keep_s[128];
    __shared__ float2 pmk[132];          // packed (barkf[i], mc[i]) for the scan
    __shared__ int   wcnt[4];
    __shared__ float red[4];

    const int t = blockIdx.x, tid = threadIdx.x;
    const int lane = tid & 63, wid = tid >> 6;
    const float pmax   = psdmax[0];
    const float shift0 = 96.0f - pmax;

    // tables from global + frame PSD into LDS
    for (int f = tid; f < FBINS; f += 256) {
        barkf[f]  = tab[TAB_BARK + f];
        athp_s[f] = tab[TAB_ATHP + f];
        float pv = shift0 + psd_db[t * FBINS + f];
        p_s[f]  = pv;
        pw_s[f] = exp10f(pv / 10.0f);
    }
    __syncthreads();

    // local-max + tonal masker level for f = tid (bin 256 can't be interior)
    float m = -1e30f;
    int   pred = 0;
    if (tid >= 1 && tid <= 255) {
        float pc = p_s[tid];
        if (pc > p_s[tid - 1] && pc > p_s[tid + 1]) {
            m = 10.0f * log10f((pw_s[tid] + pw_s[tid - 1]) + pw_s[tid + 1]);
            if (m > tab[TAB_ATHDB + tid]) pred = 1;
        }
    }
    // ballot stream-compaction (stable in frequency order)
    unsigned long long bal = __ballot(pred);
    if (lane == 0) wcnt[wid] = __popcll(bal);
    __syncthreads();
    int base = 0;
    for (int w = 0; w < wid; ++w) base += wcnt[w];
    const int n_total = wcnt[0] + wcnt[1] + wcnt[2] + wcnt[3];
    if (pred) {
        int pos = base + __popcll(bal & ((1ull << lane) - 1));
        bin_s[pos] = tid; mc_s[pos] = m; keep_s[pos] = 1;
    }
    __syncthreads();

    // pack (barkf[i], mc[i]) pairs (position-indexed bark, faithful to source)
    // + one sentinel so the scan's i+1 prefetch never reads garbage semantics
    if (tid <= n_total && tid < 130) {
        pmk[tid] = (tid < n_total) ? make_float2(barkf[tid], mc_s[tid])
                                   : make_float2(1.0e30f, -1.0e30f);
    }
    __syncthreads();

    // the inherently-sequential i_prev scan, software-pipelined: i_prev state
    // in registers, packed b64 loads, [i+1] prefetched one iteration ahead.
    // Critical path per iter: compare+select (the ds_read for i_prev+1 is the
    // only load that can stall, and only on the close&prev_smaller path).
    if (tid == 0 && n_total > 1) {
        int   i_prev = 0;
        float bp = pmk[0].x, mp = pmk[0].y;   // values at i_prev
        float2 c = pmk[1];                     // values at i
        for (int i = 1; i < n_total; ++i) {
            float2 nx = pmk[i + 1];            // prefetch next i (sentinel-safe)
            bool close        = (c.x - bp) < 0.5f;
            bool prev_smaller = mp < c.y;
            if (close) {
                keep_s[prev_smaller ? i_prev : i] = 0;
                if (prev_smaller) {
                    ++i_prev;
                    if (i_prev == i) { bp = c.x; mp = c.y; }
                    else { float2 p = pmk[i_prev]; bp = p.x; mp = p.y; }
                }
            } else {
                i_prev = i; bp = c.x; mp = c.y;
            }
            c = nx;
        }
    }
    __syncthreads();

    // compact kept maskers (ballot again), precompute per-masker terms
    int pred2 = (tid < n_total) && keep_s[tid];
    unsigned long long bal2 = __ballot(pred2);
    if (lane == 0) wcnt[wid] = __popcll(bal2);
    __syncthreads();
    int base2 = 0;
    for (int w = 0; w < wid; ++w) base2 += wcnt[w];
    const int nk = wcnt[0] + wcnt[1] + wcnt[2] + wcnt[3];
    if (pred2) {
        int pos = base2 + __popcll(bal2 & ((1ull << lane) - 1));
        int   fb = bin_s[tid];
        float mc = mc_s[tid];
        shift_s[pos] = mc + (-6.025f - 0.275f * barkf[fb]);
        barkm_s[pos] = barkf[fb];
        ups_s[pos]   = -27.0f + 0.37f * fmaxf(mc - 40.0f, 0.0f);
    }
    __syncthreads();

    // per-bin threshold power + loss (threshold kept in POWER domain:
    // 10^(10*log10(X)/10) == X — skip the log/exp round-trip)
    const float C = 3981071705.534973f / exp10f(pmax / 10.0f);  // 10^9.6/10^(pmax/10)
    float lsum = 0.0f;
    for (int f = tid; f < FBINS; f += 256) {
        float bf  = barkf[f];
        float acc = 0.0f;
        for (int k = 0; k < nk; ++k) {
            float dz    = bf - barkm_s[k];
            float slope = (dz > 0.0f) ? ups_s[k] : 27.0f;
            float tdb   = shift_s[k] + slope * dz;
            acc += exp10f(tdb / 10.0f);
        }
        float thrpow = acc + athp_s[f];
        float pds    = C * pd[t * FBINS + f];
        lsum += fmaxf(pds - thrpow, 0.0f);
    }
    for (int off = 32; off > 0; off >>= 1) lsum += __shfl_down(lsum, off);
    if ((tid & 63) == 0) red[tid >> 6] = lsum;
    __syncthreads();
    if (tid == 0) floss[t] = (red[0] + red[1]) + (red[2] + red[3]);
}

// ---------------------------------------------------------------- kernel 4
__global__ __launch_bounds__(256) void k4_final(
    const float* __restrict__ floss, int nf, float* __restrict__ out)
{
    __shared__ float red[4];
    float s = 0.0f;
    for (int i = threadIdx.x; i < nf; i += 256) s += floss[i];
    for (int off = 32; off > 0; off >>= 1) s += __shfl_down(s, off);
    if ((threadIdx.x & 63) == 0) red[threadIdx.x >> 6] = s;
    __syncthreads();
    if (threadIdx.x == 0) {
        float total = (red[0] + red[1]) + (red[2] + red[3]);
        out[0] = 1e-6f * (total / (float)(nf * FBINS));
    }
}

// ---------------------------------------------------------------- launch
extern "C" void kernel_launch(void* const* d_in, const int* in_sizes, int n_in,
                              void* d_out, int out_size, void* d_ws, size_t ws_size,
                              hipStream_t stream)
{
    const float* x_adv = (const float*)d_in[0];
    const float* x_ref = (const float*)d_in[1];
    float*       out   = (float*)d_out;

    const int L  = in_sizes[0];
    const int nf = (L - 512) / 128 + 1;           // 1247 for L=160000

    // workspace layout (floats)
    float* ws      = (float*)d_ws;
    float* tab     = ws;                                   // TAB_FLOATS
    float* psd_db  = ws + TAB_FLOATS;                      // nf*257
    float* pd      = psd_db + (size_t)nf * FBINS;          // nf*257
    float* fmaxs   = pd + (size_t)nf * FBINS;              // nf
    float* floss   = fmaxs + nf;                           // nf
    float* psdmax  = floss + nf;                           // 1

    k0_init     <<<3,  256, 0, stream>>>(tab);
    k1_stft     <<<nf, 256, 0, stream>>>(x_adv, x_ref, tab, psd_db, pd, fmaxs);
    k2_max      <<<1,  256, 0, stream>>>(fmaxs, nf, psdmax);
    k3_threshold<<<nf, 256, 0, stream>>>(tab, psd_db, pd, psdmax, floss);
    k4_final    <<<1,  256, 0, stream>>>(floss, nf, out);
}

// Round 4
// 85.039 us; speedup vs baseline: 1.3129x; 1.0496x over previous
//
#include <hip/hip_runtime.h>
#include <math.h>

// FrequencyMaskingLoss — psychoacoustic masking loss (forward only, scalar out).
// Pipeline (4 launches):
//   [K0] <<<3,256>>>  constant tables (f64 math), block-specialized
//   [K1] <<<nf,256>>> STFT(ref & delta via one complex FFT) + per-frame PSD + max
//        - register/shuffle FFT: each thread holds 2 complex elems; stages 1-7
//          in VGPRs with __shfl_xor transitions (dist 1..32); only the two
//          cross-wave transitions (64,128) touch LDS. Butterfly order, twiddle
//          values, and expressions identical to the 9-stage LDS DIT -> bitwise
//          identical spectra. Barriers 11 -> 5, DS ops ~90 -> ~20 per thread.
//   [K3] <<<nf,256>>> fused global-max (k2's exact reduction, redundant per
//        block -> bitwise-same pmax) + masking threshold + loss partial
//        - serial i_prev scan software-pipelined (regs + 1-iter prefetch)
//   [K4] <<<1,256>>>  mean -> out[0]
// WINDOW=512, HOP=128, F=257, n_frames=(L-512)/128+1 (=1247 for L=160000).

#define FBINS 257

// table layout inside ws (floats): barkf[257] | athdb[257] | athp[257] |
//                                  hann[512] | twr[256] | twi[256]   (= 1795)
#define TAB_BARK  0
#define TAB_ATHDB 257
#define TAB_ATHP  514
#define TAB_HANN  771
#define TAB_TWR   1283
#define TAB_TWI   1539
#define TAB_FLOATS 2048   // padded

// ---------------------------------------------------------------- kernel 0
// 3 blocks on 3 CUs: block0 = freq tables, block1 = hann, block2 = twiddles.
// All double-precision table math lives here (frame-invariant).
__global__ __launch_bounds__(256) void k0_init(float* __restrict__ tab)
{
    const int tid = threadIdx.x;
    const double TWO_PI = 6.283185307179586476925286766559;
    if (blockIdx.x == 0) {
        for (int f = tid; f < FBINS; f += 256) {
            double freq = 31.25 * (double)f;            // SR/2/256 * f, exact
            double q    = freq / 7500.0;
            tab[TAB_BARK + f] = (float)(13.0 * atan(0.00076 * freq) + 3.5 * atan(q * q));
            if (f == 0) {
                tab[TAB_ATHDB] = -INFINITY;
                tab[TAB_ATHP]  = 0.0f;
            } else {
                double fk = freq * 0.001;
                double ad = 3.64 * pow(fk, -0.8)
                          - 6.5 * exp(-0.6 * (fk - 3.3) * (fk - 3.3))
                          + 0.001 * fk * fk * fk * fk - 12.0;
                float av = (float)ad;
                tab[TAB_ATHDB + f] = av;
                tab[TAB_ATHP  + f] = exp10f(av / 10.0f);
            }
        }
    } else if (blockIdx.x == 1) {
        for (int n = tid; n < 512; n += 256) {
            double cw = cos((TWO_PI * (double)n) / 512.0);
            tab[TAB_HANN + n] = (float)(0.5 * (1.0 - cw));
        }
    } else {
        for (int j = tid; j < 256; j += 256) {
            double s, c;
            sincos(-(TWO_PI / 512.0) * (double)j, &s, &c);
            tab[TAB_TWR + j] = (float)c;
            tab[TAB_TWI + j] = (float)s;
        }
    }
}

// ---------------------------------------------------------------- kernel 1
// One frame per block; z = hann*ref + i*hann*delta -> one 512-pt complex FFT.
// Register-resident radix-2 DIT: thread t holds elements {2t, 2t+1} of the
// bit-reversed array; after each stage the exchange network re-pairs so the
// next stage's butterfly is again in-thread.
__global__ __launch_bounds__(256) void k1_stft(
    const float* __restrict__ xadv, const float* __restrict__ xref,
    const float* __restrict__ tab,
    float* __restrict__ psd_db, float* __restrict__ pd, float* __restrict__ fmaxs)
{
    __shared__ float2 tw2[256];
    __shared__ float2 bufA[256], bufB[256];
    __shared__ float2 zf[512];
    __shared__ float wmax[4];
    const int t = blockIdx.x, tid = threadIdx.x;

    tw2[tid] = make_float2(tab[TAB_TWR + tid], tab[TAB_TWI + tid]);

    // bit-reversed load: elem[2t] = w[n0]*x[n0], n0 = brev8(t); elem[2t+1] -> n0+256
    const int base_idx = t * 128;
    const int n0 = (int)(__brev((unsigned)tid) >> 24);
    const int n1 = n0 + 256;
    float w0 = tab[TAB_HANN + n0], w1 = tab[TAB_HANN + n1];
    float r0 = xref[base_idx + n0], r1 = xref[base_idx + n1];
    float a0 = xadv[base_idx + n0], a1 = xadv[base_idx + n1];
    float2 E0 = make_float2(w0 * r0, w0 * (a0 - r0));
    float2 E1 = make_float2(w1 * r1, w1 * (a1 - r1));
    __syncthreads();   // tw2 ready

    // stages 1..7; shfl re-pair transitions after stages 1..6
    #pragma unroll
    for (int s = 1; s <= 7; ++s) {
        const int half  = 1 << (s - 1);
        const int tstep = 512 >> s;
        float2 w = tw2[(tid & (half - 1)) * tstep];
        float vr = E1.x * w.x - E1.y * w.y;
        float vi = E1.x * w.y + E1.y * w.x;
        float ur = E0.x, ui = E0.y;
        E0 = make_float2(ur + vr, ui + vi);
        E1 = make_float2(ur - vr, ui - vi);
        if (s <= 6) {
            const int d = 1 << (s - 1);
            int b = (tid >> (s - 1)) & 1;
            float2 keep = b ? E1 : E0;
            float2 send = b ? E0 : E1;
            float2 recv;
            recv.x = __shfl_xor(send.x, d);
            recv.y = __shfl_xor(send.y, d);
            E0 = b ? recv : keep;
            E1 = b ? keep : recv;
        }
    }
    // cross-wave re-pair (distance 64) via LDS
    {
        int b = (tid >> 6) & 1;
        float2 keep = b ? E1 : E0;
        bufA[tid] = b ? E0 : E1;
        __syncthreads();
        float2 recv = bufA[tid ^ 64];
        E0 = b ? recv : keep;
        E1 = b ? keep : recv;
    }
    // stage 8: half=128, tstep=2
    {
        float2 w = tw2[(tid & 127) * 2];
        float vr = E1.x * w.x - E1.y * w.y;
        float vi = E1.x * w.y + E1.y * w.x;
        float ur = E0.x, ui = E0.y;
        E0 = make_float2(ur + vr, ui + vi);
        E1 = make_float2(ur - vr, ui - vi);
    }
    // cross-wave re-pair (distance 128) via LDS
    {
        int b = (tid >> 7) & 1;
        float2 keep = b ? E1 : E0;
        bufB[tid] = b ? E0 : E1;
        __syncthreads();
        float2 recv = bufB[tid ^ 128];
        E0 = b ? recv : keep;
        E1 = b ? keep : recv;
    }
    // stage 9: half=256, tstep=1; thread t then holds z[t], z[t+256]
    {
        float2 w = tw2[tid];
        float vr = E1.x * w.x - E1.y * w.y;
        float vi = E1.x * w.y + E1.y * w.x;
        float ur = E0.x, ui = E0.y;
        E0 = make_float2(ur + vr, ui + vi);
        E1 = make_float2(ur - vr, ui - vi);
    }
    zf[tid]       = E0;
    zf[tid + 256] = E1;
    __syncthreads();

    // unpack A=rfft(ref), B=rfft(delta); PSDs
    const float S2 = 1.0172526041666667e-05f;   // (sqrt(8/3)/512)^2
    float lmax = -1e30f;
    for (int k = tid; k <= 256; k += 256) {
        int nk = (512 - k) & 511;
        float2 zk = zf[k];
        float2 zn = zf[nk];
        float ar = 0.5f * (zk.x + zn.x), ai = 0.5f * (zk.y - zn.y);   // ref spectrum
        float br = 0.5f * (zk.y + zn.y), bi = 0.5f * (zn.x - zk.x);   // delta spectrum
        float prefp = S2 * (ar * ar + ai * ai);
        float pdb   = fmaxf(10.0f * log10f(prefp), -200.0f);
        psd_db[t * FBINS + k] = pdb;
        pd[t * FBINS + k]     = S2 * (br * br + bi * bi);
        lmax = fmaxf(lmax, pdb);
    }
    for (int off = 32; off > 0; off >>= 1) lmax = fmaxf(lmax, __shfl_down(lmax, off));
    if ((tid & 63) == 0) wmax[tid >> 6] = lmax;
    __syncthreads();
    if (tid == 0)
        fmaxs[t] = fmaxf(fmaxf(wmax[0], wmax[1]), fmaxf(wmax[2], wmax[3]));
}

// ---------------------------------------------------------------- kernel 3
// Fuses the old k2: every block reduces fmaxs with the identical reduction
// order -> bitwise-same pmax, one launch fewer. No atomics.
__global__ __launch_bounds__(256) void k3_threshold(
    const float* __restrict__ tab,
    const float* __restrict__ psd_db, const float* __restrict__ pd,
    const float* __restrict__ fmaxs, int nf, float* __restrict__ floss)
{
    __shared__ float barkf[FBINS], athp_s[FBINS];
    __shared__ float p_s[FBINS], pw_s[FBINS];
    __shared__ float mc_s[128], shift_s[128], barkm_s[128], ups_s[128];
    __shared__ int   bin_s[128], keep_s[128];
    __shared__ float2 pmk[132];          // packed (barkf[i], mc[i]) for the scan
    __shared__ int   wcnt[4];
    __shared__ float red[4];
    __shared__ float sm[4];

    const int t = blockIdx.x, tid = threadIdx.x;
    const int lane = tid & 63, wid = tid >> 6;

    // prefetch this frame's PSD bins (overlap latency with the max reduce)
    const float pdb_a = psd_db[t * FBINS + tid];
    const float pdb_b = psd_db[t * FBINS + 256];

    // tables into LDS + global psd_max (k2's exact reduction order)
    for (int f = tid; f < FBINS; f += 256) {
        barkf[f]  = tab[TAB_BARK + f];
        athp_s[f] = tab[TAB_ATHP + f];
    }
    float v = -1e30f;
    for (int i = tid; i < nf; i += 256) v = fmaxf(v, fmaxs[i]);
    for (int off = 32; off > 0; off >>= 1) v = fmaxf(v, __shfl_down(v, off));
    if (lane == 0) sm[wid] = v;
    __syncthreads();
    const float pmax   = fmaxf(fmaxf(sm[0], sm[1]), fmaxf(sm[2], sm[3]));
    const float shift0 = 96.0f - pmax;

    {
        float pv = shift0 + pdb_a;
        p_s[tid]  = pv;
        pw_s[tid] = exp10f(pv / 10.0f);
        if (tid == 0) {
            float pv2 = shift0 + pdb_b;
            p_s[256]  = pv2;
            pw_s[256] = exp10f(pv2 / 10.0f);
        }
    }
    __syncthreads();

    // local-max + tonal masker level for f = tid (bin 256 can't be interior)
    float m = -1e30f;
    int   pred = 0;
    if (tid >= 1 && tid <= 255) {
        float pc = p_s[tid];
        if (pc > p_s[tid - 1] && pc > p_s[tid + 1]) {
            m = 10.0f * log10f((pw_s[tid] + pw_s[tid - 1]) + pw_s[tid + 1]);
            if (m > tab[TAB_ATHDB + tid]) pred = 1;
        }
    }
    // ballot stream-compaction (stable in frequency order)
    unsigned long long bal = __ballot(pred);
    if (lane == 0) wcnt[wid] = __popcll(bal);
    __syncthreads();
    int base = 0;
    for (int w = 0; w < wid; ++w) base += wcnt[w];
    const int n_total = wcnt[0] + wcnt[1] + wcnt[2] + wcnt[3];
    if (pred) {
        int pos = base + __popcll(bal & ((1ull << lane) - 1));
        bin_s[pos] = tid; mc_s[pos] = m; keep_s[pos] = 1;
    }
    __syncthreads();

    // pack (barkf[i], mc[i]) pairs (position-indexed bark, faithful to source)
    // + one sentinel so the scan's i+1 prefetch never reads garbage semantics
    if (tid <= n_total && tid < 130) {
        pmk[tid] = (tid < n_total) ? make_float2(barkf[tid], mc_s[tid])
                                   : make_float2(1.0e30f, -1.0e30f);
    }
    __syncthreads();

    // the inherently-sequential i_prev scan, software-pipelined: i_prev state
    // in registers, packed b64 loads, [i+1] prefetched one iteration ahead.
    if (tid == 0 && n_total > 1) {
        int   i_prev = 0;
        float bp = pmk[0].x, mp = pmk[0].y;   // values at i_prev
        float2 c = pmk[1];                     // values at i
        for (int i = 1; i < n_total; ++i) {
            float2 nx = pmk[i + 1];            // prefetch next i (sentinel-safe)
            bool close        = (c.x - bp) < 0.5f;
            bool prev_smaller = mp < c.y;
            if (close) {
                keep_s[prev_smaller ? i_prev : i] = 0;
                if (prev_smaller) {
                    ++i_prev;
                    if (i_prev == i) { bp = c.x; mp = c.y; }
                    else { float2 p = pmk[i_prev]; bp = p.x; mp = p.y; }
                }
            } else {
                i_prev = i; bp = c.x; mp = c.y;
            }
            c = nx;
        }
    }
    __syncthreads();

    // compact kept maskers (ballot again), precompute per-masker terms
    int pred2 = (tid < n_total) && keep_s[tid];
    unsigned long long bal2 = __ballot(pred2);
    if (lane == 0) wcnt[wid] = __popcll(bal2);
    __syncthreads();
    int base2 = 0;
    for (int w = 0; w < wid; ++w) base2 += wcnt[w];
    const int nk = wcnt[0] + wcnt[1] + wcnt[2] + wcnt[3];
    if (pred2) {
        int pos = base2 + __popcll(bal2 & ((1ull << lane) - 1));
        int   fb = bin_s[tid];
        float mc = mc_s[tid];
        shift_s[pos] = mc + (-6.025f - 0.275f * barkf[fb]);
        barkm_s[pos] = barkf[fb];
        ups_s[pos]   = -27.0f + 0.37f * fmaxf(mc - 40.0f, 0.0f);
    }
    __syncthreads();

    // per-bin threshold power + loss (threshold kept in POWER domain:
    // 10^(10*log10(X)/10) == X — skip the log/exp round-trip)
    const float C = 3981071705.534973f / exp10f(pmax / 10.0f);  // 10^9.6/10^(pmax/10)
    float lsum = 0.0f;
    for (int f = tid; f < FBINS; f += 256) {
        float bf  = barkf[f];
        float acc = 0.0f;
        for (int k = 0; k < nk; ++k) {
            float dz    = bf - barkm_s[k];
            float slope = (dz > 0.0f) ? ups_s[k] : 27.0f;
            float tdb   = shift_s[k] + slope * dz;
            acc += exp10f(tdb / 10.0f);
        }
        float thrpow = acc + athp_s[f];
        float pds    = C * pd[t * FBINS + f];
        lsum += fmaxf(pds - thrpow, 0.0f);
    }
    for (int off = 32; off > 0; off >>= 1) lsum += __shfl_down(lsum, off);
    if ((tid & 63) == 0) red[tid >> 6] = lsum;
    __syncthreads();
    if (tid == 0) floss[t] = (red[0] + red[1]) + (red[2] + red[3]);
}

// ---------------------------------------------------------------- kernel 4
__global__ __launch_bounds__(256) void k4_final(
    const float* __restrict__ floss, int nf, float* __restrict__ out)
{
    __shared__ float red[4];
    float s = 0.0f;
    for (int i = threadIdx.x; i < nf; i += 256) s += floss[i];
    for (int off = 32; off > 0; off >>= 1) s += __shfl_down(s, off);
    if ((threadIdx.x & 63) == 0) red[threadIdx.x >> 6] = s;
    __syncthreads();
    if (threadIdx.x == 0) {
        float total = (red[0] + red[1]) + (red[2] + red[3]);
        out[0] = 1e-6f * (total / (float)(nf * FBINS));
    }
}

// ---------------------------------------------------------------- launch
extern "C" void kernel_launch(void* const* d_in, const int* in_sizes, int n_in,
                              void* d_out, int out_size, void* d_ws, size_t ws_size,
                              hipStream_t stream)
{
    const float* x_adv = (const float*)d_in[0];
    const float* x_ref = (const float*)d_in[1];
    float*       out   = (float*)d_out;

    const int L  = in_sizes[0];
    const int nf = (L - 512) / 128 + 1;           // 1247 for L=160000

    // workspace layout (floats)
    float* ws      = (float*)d_ws;
    float* tab     = ws;                                   // TAB_FLOATS
    float* psd_db  = ws + TAB_FLOATS;                      // nf*257
    float* pd      = psd_db + (size_t)nf * FBINS;          // nf*257
    float* fmaxs   = pd + (size_t)nf * FBINS;              // nf
    float* floss   = fmaxs + nf;                           // nf

    k0_init     <<<3,  256, 0, stream>>>(tab);
    k1_stft     <<<nf, 256, 0, stream>>>(x_adv, x_ref, tab, psd_db, pd, fmaxs);
    k3_threshold<<<nf, 256, 0, stream>>>(tab, psd_db, pd, fmaxs, nf, floss);
    k4_final    <<<1,  256, 0, stream>>>(floss, nf, out);
}

// Round 5
// 84.990 us; speedup vs baseline: 1.3136x; 1.0006x over previous
//
#include <hip/hip_runtime.h>
#include <hip/hip_cooperative_groups.h>
#include <math.h>

namespace cg = cooperative_groups;

// FrequencyMaskingLoss — psychoacoustic masking loss (forward only, scalar out).
//
// PRIMARY PATH (1 launch): cooperative kernel kfused, grid = nf blocks:
//   phase A: per-block hann/tw tables (f64, bitwise == k0) + register/shuffle
//            FFT (verbatim round-4 k1) -> frame psd/pd kept in LDS; block 0
//            also writes bark/ATH tables to global tab; fmaxs[t] to global.
//   grid.sync()
//   phase B: verbatim k3 (global pmax reduce, maskers, serial scan, loss),
//            psd/pd sourced from LDS -> floss[t].
//   grid.sync()
//   phase C: block 0 = verbatim k4 reduction -> out[0].
// FALLBACK PATH (4 launches, proven round-4 code): if cooperative occupancy
// or launch is unavailable.
// WINDOW=512, HOP=128, F=257, n_frames=(L-512)/128+1 (=1247 for L=160000).

#define FBINS 257

// table layout inside ws (floats)
#define TAB_BARK  0
#define TAB_ATHDB 257
#define TAB_ATHP  514
#define TAB_HANN  771
#define TAB_TWR   1283
#define TAB_TWI   1539
#define TAB_FLOATS 2048   // padded

// ================================================================ FUSED
__global__ __launch_bounds__(256, 5) void kfused(
    const float* __restrict__ xadv, const float* __restrict__ xref,
    float* __restrict__ tab, float* __restrict__ fmaxs,
    float* __restrict__ floss, int nf, float* __restrict__ out)
{
    __shared__ float  hannS[512];
    __shared__ float2 tw2[256];
    __shared__ float2 bufA[256], bufB[256];
    __shared__ float2 zf[512];
    __shared__ float  wmax[4];
    __shared__ float  psdS[FBINS];   // persists A -> B
    __shared__ float  pdS[FBINS];    // persists A -> B
    // phase B
    __shared__ float  barkf[FBINS], athp_s[FBINS];
    __shared__ float  p_s[FBINS], pw_s[FBINS];
    __shared__ float  mc_s[128], shift_s[128], barkm_s[128], ups_s[128];
    __shared__ int    bin_s[128], keep_s[128];
    __shared__ float2 pmk[132];
    __shared__ int    wcnt[4];
    __shared__ float  red[4];
    __shared__ float  sm[4];

    const int t = blockIdx.x, tid = threadIdx.x;
    const int lane = tid & 63, wid = tid >> 6;
    const double TWO_PI = 6.283185307179586476925286766559;

    // ---------------- phase A0: tables (bitwise == k0's expressions)
    for (int n = tid; n < 512; n += 256)
        hannS[n] = (float)(0.5 * (1.0 - cos((TWO_PI * (double)n) / 512.0)));
    {
        double s, c;
        sincos(-(TWO_PI / 512.0) * (double)tid, &s, &c);
        tw2[tid] = make_float2((float)c, (float)s);
    }
    if (t == 0) {
        for (int f = tid; f < FBINS; f += 256) {
            double freq = 31.25 * (double)f;
            double q    = freq / 7500.0;
            tab[TAB_BARK + f] = (float)(13.0 * atan(0.00076 * freq) + 3.5 * atan(q * q));
            if (f == 0) {
                tab[TAB_ATHDB] = -INFINITY;
                tab[TAB_ATHP]  = 0.0f;
            } else {
                double fk = freq * 0.001;
                double ad = 3.64 * pow(fk, -0.8)
                          - 6.5 * exp(-0.6 * (fk - 3.3) * (fk - 3.3))
                          + 0.001 * fk * fk * fk * fk - 12.0;
                float av = (float)ad;
                tab[TAB_ATHDB + f] = av;
                tab[TAB_ATHP  + f] = exp10f(av / 10.0f);
            }
        }
    }
    __syncthreads();

    // ---------------- phase A1: register/shuffle FFT (verbatim round-4 k1)
    const int base_idx = t * 128;
    const int n0 = (int)(__brev((unsigned)tid) >> 24);
    const int n1 = n0 + 256;
    float w0 = hannS[n0], w1 = hannS[n1];
    float r0 = xref[base_idx + n0], r1 = xref[base_idx + n1];
    float a0 = xadv[base_idx + n0], a1 = xadv[base_idx + n1];
    float2 E0 = make_float2(w0 * r0, w0 * (a0 - r0));
    float2 E1 = make_float2(w1 * r1, w1 * (a1 - r1));

    #pragma unroll
    for (int s = 1; s <= 7; ++s) {
        const int half  = 1 << (s - 1);
        const int tstep = 512 >> s;
        float2 w = tw2[(tid & (half - 1)) * tstep];
        float vr = E1.x * w.x - E1.y * w.y;
        float vi = E1.x * w.y + E1.y * w.x;
        float ur = E0.x, ui = E0.y;
        E0 = make_float2(ur + vr, ui + vi);
        E1 = make_float2(ur - vr, ui - vi);
        if (s <= 6) {
            const int d = 1 << (s - 1);
            int b = (tid >> (s - 1)) & 1;
            float2 keep = b ? E1 : E0;
            float2 send = b ? E0 : E1;
            float2 recv;
            recv.x = __shfl_xor(send.x, d);
            recv.y = __shfl_xor(send.y, d);
            E0 = b ? recv : keep;
            E1 = b ? keep : recv;
        }
    }
    {
        int b = (tid >> 6) & 1;
        float2 keep = b ? E1 : E0;
        bufA[tid] = b ? E0 : E1;
        __syncthreads();
        float2 recv = bufA[tid ^ 64];
        E0 = b ? recv : keep;
        E1 = b ? keep : recv;
    }
    {
        float2 w = tw2[(tid & 127) * 2];
        float vr = E1.x * w.x - E1.y * w.y;
        float vi = E1.x * w.y + E1.y * w.x;
        float ur = E0.x, ui = E0.y;
        E0 = make_float2(ur + vr, ui + vi);
        E1 = make_float2(ur - vr, ui - vi);
    }
    {
        int b = (tid >> 7) & 1;
        float2 keep = b ? E1 : E0;
        bufB[tid] = b ? E0 : E1;
        __syncthreads();
        float2 recv = bufB[tid ^ 128];
        E0 = b ? recv : keep;
        E1 = b ? keep : recv;
    }
    {
        float2 w = tw2[tid];
        float vr = E1.x * w.x - E1.y * w.y;
        float vi = E1.x * w.y + E1.y * w.x;
        float ur = E0.x, ui = E0.y;
        E0 = make_float2(ur + vr, ui + vi);
        E1 = make_float2(ur - vr, ui - vi);
    }
    zf[tid]       = E0;
    zf[tid + 256] = E1;
    __syncthreads();

    // unpack -> LDS psd/pd; frame max -> global fmaxs
    const float S2 = 1.0172526041666667e-05f;   // (sqrt(8/3)/512)^2
    float lmax = -1e30f;
    for (int k = tid; k <= 256; k += 256) {
        int nk = (512 - k) & 511;
        float2 zk = zf[k];
        float2 zn = zf[nk];
        float ar = 0.5f * (zk.x + zn.x), ai = 0.5f * (zk.y - zn.y);
        float br = 0.5f * (zk.y + zn.y), bi = 0.5f * (zn.x - zk.x);
        float prefp = S2 * (ar * ar + ai * ai);
        float pdb   = fmaxf(10.0f * log10f(prefp), -200.0f);
        psdS[k] = pdb;
        pdS[k]  = S2 * (br * br + bi * bi);
        lmax = fmaxf(lmax, pdb);
    }
    for (int off = 32; off > 0; off >>= 1) lmax = fmaxf(lmax, __shfl_down(lmax, off));
    if ((tid & 63) == 0) wmax[tid >> 6] = lmax;
    __syncthreads();
    if (tid == 0)
        fmaxs[t] = fmaxf(fmaxf(wmax[0], wmax[1]), fmaxf(wmax[2], wmax[3]));

    // ---------------- grid-wide sync #1 (psd_max dependency)
    cg::this_grid().sync();

    // ---------------- phase B: threshold (verbatim k3, LDS psd/pd)
    for (int f = tid; f < FBINS; f += 256) {
        barkf[f]  = tab[TAB_BARK + f];
        athp_s[f] = tab[TAB_ATHP + f];
    }
    float v = -1e30f;
    for (int i = tid; i < nf; i += 256) v = fmaxf(v, fmaxs[i]);
    for (int off = 32; off > 0; off >>= 1) v = fmaxf(v, __shfl_down(v, off));
    if (lane == 0) sm[wid] = v;
    __syncthreads();
    const float pmax   = fmaxf(fmaxf(sm[0], sm[1]), fmaxf(sm[2], sm[3]));
    const float shift0 = 96.0f - pmax;

    {
        float pv = shift0 + psdS[tid];
        p_s[tid]  = pv;
        pw_s[tid] = exp10f(pv / 10.0f);
        if (tid == 0) {
            float pv2 = shift0 + psdS[256];
            p_s[256]  = pv2;
            pw_s[256] = exp10f(pv2 / 10.0f);
        }
    }
    __syncthreads();

    float m = -1e30f;
    int   pred = 0;
    if (tid >= 1 && tid <= 255) {
        float pc = p_s[tid];
        if (pc > p_s[tid - 1] && pc > p_s[tid + 1]) {
            m = 10.0f * log10f((pw_s[tid] + pw_s[tid - 1]) + pw_s[tid + 1]);
            if (m > tab[TAB_ATHDB + tid]) pred = 1;
        }
    }
    unsigned long long bal = __ballot(pred);
    if (lane == 0) wcnt[wid] = __popcll(bal);
    __syncthreads();
    int base = 0;
    for (int w = 0; w < wid; ++w) base += wcnt[w];
    const int n_total = wcnt[0] + wcnt[1] + wcnt[2] + wcnt[3];
    if (pred) {
        int pos = base + __popcll(bal & ((1ull << lane) - 1));
        bin_s[pos] = tid; mc_s[pos] = m; keep_s[pos] = 1;
    }
    __syncthreads();

    if (tid <= n_total && tid < 130) {
        pmk[tid] = (tid < n_total) ? make_float2(barkf[tid], mc_s[tid])
                                   : make_float2(1.0e30f, -1.0e30f);
    }
    __syncthreads();

    if (tid == 0 && n_total > 1) {
        int   i_prev = 0;
        float bp = pmk[0].x, mp = pmk[0].y;
        float2 c = pmk[1];
        for (int i = 1; i < n_total; ++i) {
            float2 nx = pmk[i + 1];
            bool close        = (c.x - bp) < 0.5f;
            bool prev_smaller = mp < c.y;
            if (close) {
                keep_s[prev_smaller ? i_prev : i] = 0;
                if (prev_smaller) {
                    ++i_prev;
                    if (i_prev == i) { bp = c.x; mp = c.y; }
                    else { float2 p = pmk[i_prev]; bp = p.x; mp = p.y; }
                }
            } else {
                i_prev = i; bp = c.x; mp = c.y;
            }
            c = nx;
        }
    }
    __syncthreads();

    int pred2 = (tid < n_total) && keep_s[tid];
    unsigned long long bal2 = __ballot(pred2);
    if (lane == 0) wcnt[wid] = __popcll(bal2);
    __syncthreads();
    int base2 = 0;
    for (int w = 0; w < wid; ++w) base2 += wcnt[w];
    const int nk2 = wcnt[0] + wcnt[1] + wcnt[2] + wcnt[3];
    if (pred2) {
        int pos = base2 + __popcll(bal2 & ((1ull << lane) - 1));
        int   fb = bin_s[tid];
        float mc = mc_s[tid];
        shift_s[pos] = mc + (-6.025f - 0.275f * barkf[fb]);
        barkm_s[pos] = barkf[fb];
        ups_s[pos]   = -27.0f + 0.37f * fmaxf(mc - 40.0f, 0.0f);
    }
    __syncthreads();

    const float C = 3981071705.534973f / exp10f(pmax / 10.0f);  // 10^9.6/10^(pmax/10)
    float lsum = 0.0f;
    for (int f = tid; f < FBINS; f += 256) {
        float bf  = barkf[f];
        float acc = 0.0f;
        for (int k = 0; k < nk2; ++k) {
            float dz    = bf - barkm_s[k];
            float slope = (dz > 0.0f) ? ups_s[k] : 27.0f;
            float tdb   = shift_s[k] + slope * dz;
            acc += exp10f(tdb / 10.0f);
        }
        float thrpow = acc + athp_s[f];
        float pds    = C * pdS[f];
        lsum += fmaxf(pds - thrpow, 0.0f);
    }
    for (int off = 32; off > 0; off >>= 1) lsum += __shfl_down(lsum, off);
    if ((tid & 63) == 0) red[tid >> 6] = lsum;
    __syncthreads();
    if (tid == 0) floss[t] = (red[0] + red[1]) + (red[2] + red[3]);

    // ---------------- grid-wide sync #2 (floss complete)
    cg::this_grid().sync();

    // ---------------- phase C: block 0 = verbatim k4
    if (t == 0) {
        float s2 = 0.0f;
        for (int i = tid; i < nf; i += 256) s2 += floss[i];
        for (int off = 32; off > 0; off >>= 1) s2 += __shfl_down(s2, off);
        if ((tid & 63) == 0) red[tid >> 6] = s2;
        __syncthreads();
        if (tid == 0) {
            float total = (red[0] + red[1]) + (red[2] + red[3]);
            out[0] = 1e-6f * (total / (float)(nf * FBINS));
        }
    }
}

// ================================================================ FALLBACK
// (proven round-4 kernels, verbatim)
__global__ __launch_bounds__(256) void k0_init(float* __restrict__ tab)
{
    const int tid = threadIdx.x;
    const double TWO_PI = 6.283185307179586476925286766559;
    if (blockIdx.x == 0) {
        for (int f = tid; f < FBINS; f += 256) {
            double freq = 31.25 * (double)f;
            double q    = freq / 7500.0;
            tab[TAB_BARK + f] = (float)(13.0 * atan(0.00076 * freq) + 3.5 * atan(q * q));
            if (f == 0) {
                tab[TAB_ATHDB] = -INFINITY;
                tab[TAB_ATHP]  = 0.0f;
            } else {
                double fk = freq * 0.001;
                double ad = 3.64 * pow(fk, -0.8)
                          - 6.5 * exp(-0.6 * (fk - 3.3) * (fk - 3.3))
                          + 0.001 * fk * fk * fk * fk - 12.0;
                float av = (float)ad;
                tab[TAB_ATHDB + f] = av;
                tab[TAB_ATHP  + f] = exp10f(av / 10.0f);
            }
        }
    } else if (blockIdx.x == 1) {
        for (int n = tid; n < 512; n += 256) {
            double cw = cos((TWO_PI * (double)n) / 512.0);
            tab[TAB_HANN + n] = (float)(0.5 * (1.0 - cw));
        }
    } else {
        for (int j = tid; j < 256; j += 256) {
            double s, c;
            sincos(-(TWO_PI / 512.0) * (double)j, &s, &c);
            tab[TAB_TWR + j] = (float)c;
            tab[TAB_TWI + j] = (float)s;
        }
    }
}

__global__ __launch_bounds__(256) void k1_stft(
    const float* __restrict__ xadv, const float* __restrict__ xref,
    const float* __restrict__ tab,
    float* __restrict__ psd_db, float* __restrict__ pd, float* __restrict__ fmaxs)
{
    __shared__ float2 tw2[256];
    __shared__ float2 bufA[256], bufB[256];
    __shared__ float2 zf[512];
    __shared__ float wmax[4];
    const int t = blockIdx.x, tid = threadIdx.x;

    tw2[tid] = make_float2(tab[TAB_TWR + tid], tab[TAB_TWI + tid]);

    const int base_idx = t * 128;
    const int n0 = (int)(__brev((unsigned)tid) >> 24);
    const int n1 = n0 + 256;
    float w0 = tab[TAB_HANN + n0], w1 = tab[TAB_HANN + n1];
    float r0 = xref[base_idx + n0], r1 = xref[base_idx + n1];
    float a0 = xadv[base_idx + n0], a1 = xadv[base_idx + n1];
    float2 E0 = make_float2(w0 * r0, w0 * (a0 - r0));
    float2 E1 = make_float2(w1 * r1, w1 * (a1 - r1));
    __syncthreads();

    #pragma unroll
    for (int s = 1; s <= 7; ++s) {
        const int half  = 1 << (s - 1);
        const int tstep = 512 >> s;
        float2 w = tw2[(tid & (half - 1)) * tstep];
        float vr = E1.x * w.x - E1.y * w.y;
        float vi = E1.x * w.y + E1.y * w.x;
        float ur = E0.x, ui = E0.y;
        E0 = make_float2(ur + vr, ui + vi);
        E1 = make_float2(ur - vr, ui - vi);
        if (s <= 6) {
            const int d = 1 << (s - 1);
            int b = (tid >> (s - 1)) & 1;
            float2 keep = b ? E1 : E0;
            float2 send = b ? E0 : E1;
            float2 recv;
            recv.x = __shfl_xor(send.x, d);
            recv.y = __shfl_xor(send.y, d);
            E0 = b ? recv : keep;
            E1 = b ? keep : recv;
        }
    }
    {
        int b = (tid >> 6) & 1;
        float2 keep = b ? E1 : E0;
        bufA[tid] = b ? E0 : E1;
        __syncthreads();
        float2 recv = bufA[tid ^ 64];
        E0 = b ? recv : keep;
        E1 = b ? keep : recv;
    }
    {
        float2 w = tw2[(tid & 127) * 2];
        float vr = E1.x * w.x - E1.y * w.y;
        float vi = E1.x * w.y + E1.y * w.x;
        float ur = E0.x, ui = E0.y;
        E0 = make_float2(ur + vr, ui + vi);
        E1 = make_float2(ur - vr, ui - vi);
    }
    {
        int b = (tid >> 7) & 1;
        float2 keep = b ? E1 : E0;
        bufB[tid] = b ? E0 : E1;
        __syncthreads();
        float2 recv = bufB[tid ^ 128];
        E0 = b ? recv : keep;
        E1 = b ? keep : recv;
    }
    {
        float2 w = tw2[tid];
        float vr = E1.x * w.x - E1.y * w.y;
        float vi = E1.x * w.y + E1.y * w.x;
        float ur = E0.x, ui = E0.y;
        E0 = make_float2(ur + vr, ui + vi);
        E1 = make_float2(ur - vr, ui - vi);
    }
    zf[tid]       = E0;
    zf[tid + 256] = E1;
    __syncthreads();

    const float S2 = 1.0172526041666667e-05f;
    float lmax = -1e30f;
    for (int k = tid; k <= 256; k += 256) {
        int nk = (512 - k) & 511;
        float2 zk = zf[k];
        float2 zn = zf[nk];
        float ar = 0.5f * (zk.x + zn.x), ai = 0.5f * (zk.y - zn.y);
        float br = 0.5f * (zk.y + zn.y), bi = 0.5f * (zn.x - zk.x);
        float prefp = S2 * (ar * ar + ai * ai);
        float pdb   = fmaxf(10.0f * log10f(prefp), -200.0f);
        psd_db[t * FBINS + k] = pdb;
        pd[t * FBINS + k]     = S2 * (br * br + bi * bi);
        lmax = fmaxf(lmax, pdb);
    }
    for (int off = 32; off > 0; off >>= 1) lmax = fmaxf(lmax, __shfl_down(lmax, off));
    if ((tid & 63) == 0) wmax[tid >> 6] = lmax;
    __syncthreads();
    if (tid == 0)
        fmaxs[t] = fmaxf(fmaxf(wmax[0], wmax[1]), fmaxf(wmax[2], wmax[3]));
}

__global__ __launch_bounds__(256) void k3_threshold(
    const float* __restrict__ tab,
    const float* __restrict__ psd_db, const float* __restrict__ pd,
    const float* __restrict__ fmaxs, int nf, float* __restrict__ floss)
{
    __shared__ float barkf[FBINS], athp_s[FBINS];
    __shared__ float p_s[FBINS], pw_s[FBINS];
    __shared__ float mc_s[128], shift_s[128], barkm_s[128], ups_s[128];
    __shared__ int   bin_s[128], keep_s[128];
    __shared__ float2 pmk[132];
    __shared__ int   wcnt[4];
    __shared__ float red[4];
    __shared__ float sm[4];

    const int t = blockIdx.x, tid = threadIdx.x;
    const int lane = tid & 63, wid = tid >> 6;

    const float pdb_a = psd_db[t * FBINS + tid];
    const float pdb_b = psd_db[t * FBINS + 256];

    for (int f = tid; f < FBINS; f += 256) {
        barkf[f]  = tab[TAB_BARK + f];
        athp_s[f] = tab[TAB_ATHP + f];
    }
    float v = -1e30f;
    for (int i = tid; i < nf; i += 256) v = fmaxf(v, fmaxs[i]);
    for (int off = 32; off > 0; off >>= 1) v = fmaxf(v, __shfl_down(v, off));
    if (lane == 0) sm[wid] = v;
    __syncthreads();
    const float pmax   = fmaxf(fmaxf(sm[0], sm[1]), fmaxf(sm[2], sm[3]));
    const float shift0 = 96.0f - pmax;

    {
        float pv = shift0 + pdb_a;
        p_s[tid]  = pv;
        pw_s[tid] = exp10f(pv / 10.0f);
        if (tid == 0) {
            float pv2 = shift0 + pdb_b;
            p_s[256]  = pv2;
            pw_s[256] = exp10f(pv2 / 10.0f);
        }
    }
    __syncthreads();

    float m = -1e30f;
    int   pred = 0;
    if (tid >= 1 && tid <= 255) {
        float pc = p_s[tid];
        if (pc > p_s[tid - 1] && pc > p_s[tid + 1]) {
            m = 10.0f * log10f((pw_s[tid] + pw_s[tid - 1]) + pw_s[tid + 1]);
            if (m > tab[TAB_ATHDB + tid]) pred = 1;
        }
    }
    unsigned long long bal = __ballot(pred);
    if (lane == 0) wcnt[wid] = __popcll(bal);
    __syncthreads();
    int base = 0;
    for (int w = 0; w < wid; ++w) base += wcnt[w];
    const int n_total = wcnt[0] + wcnt[1] + wcnt[2] + wcnt[3];
    if (pred) {
        int pos = base + __popcll(bal & ((1ull << lane) - 1));
        bin_s[pos] = tid; mc_s[pos] = m; keep_s[pos] = 1;
    }
    __syncthreads();

    if (tid <= n_total && tid < 130) {
        pmk[tid] = (tid < n_total) ? make_float2(barkf[tid], mc_s[tid])
                                   : make_float2(1.0e30f, -1.0e30f);
    }
    __syncthreads();

    if (tid == 0 && n_total > 1) {
        int   i_prev = 0;
        float bp = pmk[0].x, mp = pmk[0].y;
        float2 c = pmk[1];
        for (int i = 1; i < n_total; ++i) {
            float2 nx = pmk[i + 1];
            bool close        = (c.x - bp) < 0.5f;
            bool prev_smaller = mp < c.y;
            if (close) {
                keep_s[prev_smaller ? i_prev : i] = 0;
                if (prev_smaller) {
                    ++i_prev;
                    if (i_prev == i) { bp = c.x; mp = c.y; }
                    else { float2 p = pmk[i_prev]; bp = p.x; mp = p.y; }
                }
            } else {
                i_prev = i; bp = c.x; mp = c.y;
            }
            c = nx;
        }
    }
    __syncthreads();

    int pred2 = (tid < n_total) && keep_s[tid];
    unsigned long long bal2 = __ballot(pred2);
    if (lane == 0) wcnt[wid] = __popcll(bal2);
    __syncthreads();
    int base2 = 0;
    for (int w = 0; w < wid; ++w) base2 += wcnt[w];
    const int nk = wcnt[0] + wcnt[1] + wcnt[2] + wcnt[3];
    if (pred2) {
        int pos = base2 + __popcll(bal2 & ((1ull << lane) - 1));
        int   fb = bin_s[tid];
        float mc = mc_s[tid];
        shift_s[pos] = mc + (-6.025f - 0.275f * barkf[fb]);
        barkm_s[pos] = barkf[fb];
        ups_s[pos]   = -27.0f + 0.37f * fmaxf(mc - 40.0f, 0.0f);
    }
    __syncthreads();

    const float C = 3981071705.534973f / exp10f(pmax / 10.0f);
    float lsum = 0.0f;
    for (int f = tid; f < FBINS; f += 256) {
        float bf  = barkf[f];
        float acc = 0.0f;
        for (int k = 0; k < nk; ++k) {
            float dz    = bf - barkm_s[k];
            float slope = (dz > 0.0f) ? ups_s[k] : 27.0f;
            float tdb   = shift_s[k] + slope * dz;
            acc += exp10f(tdb / 10.0f);
        }
        float thrpow = acc + athp_s[f];
        float pds    = C * pd[t * FBINS + f];
        lsum += fmaxf(pds - thrpow, 0.0f);
    }
    for (int off = 32; off > 0; off >>= 1) lsum += __shfl_down(lsum, off);
    if ((tid & 63) == 0) red[tid >> 6] = lsum;
    __syncthreads();
    if (tid == 0) floss[t] = (red[0] + red[1]) + (red[2] + red[3]);
}

__global__ __launch_bounds__(256) void k4_final(
    const float* __restrict__ floss, int nf, float* __restrict__ out)
{
    __shared__ float red[4];
    float s = 0.0f;
    for (int i = threadIdx.x; i < nf; i += 256) s += floss[i];
    for (int off = 32; off > 0; off >>= 1) s += __shfl_down(s, off);
    if ((threadIdx.x & 63) == 0) red[threadIdx.x >> 6] = s;
    __syncthreads();
    if (threadIdx.x == 0) {
        float total = (red[0] + red[1]) + (red[2] + red[3]);
        out[0] = 1e-6f * (total / (float)(nf * FBINS));
    }
}

// ---------------------------------------------------------------- launch
extern "C" void kernel_launch(void* const* d_in, const int* in_sizes, int n_in,
                              void* d_out, int out_size, void* d_ws, size_t ws_size,
                              hipStream_t stream)
{
    const float* x_adv = (const float*)d_in[0];
    const float* x_ref = (const float*)d_in[1];
    float*       out   = (float*)d_out;

    const int L  = in_sizes[0];
    const int nf = (L - 512) / 128 + 1;           // 1247 for L=160000

    // workspace layout (floats)
    float* ws      = (float*)d_ws;
    float* tab     = ws;                                   // TAB_FLOATS
    float* psd_db  = ws + TAB_FLOATS;                      // nf*257 (fallback only)
    float* pd      = psd_db + (size_t)nf * FBINS;          // nf*257 (fallback only)
    float* fmaxs   = pd + (size_t)nf * FBINS;              // nf
    float* floss   = fmaxs + nf;                           // nf

    // cooperative-launch capacity check (cached; pure host query, capture-safe)
    static int maxB = -2;
    if (maxB == -2) {
        int mb = 0;
        if (hipOccupancyMaxActiveBlocksPerMultiprocessor(&mb, kfused, 256, 0) == hipSuccess)
            maxB = mb;
        else
            maxB = 0;
    }

    bool done = false;
    if (maxB > 0 && (long long)maxB * 256 >= (long long)nf) {
        int nf_i = nf;
        void* kargs[] = { (void*)&x_adv, (void*)&x_ref, (void*)&tab,
                          (void*)&fmaxs, (void*)&floss, (void*)&nf_i, (void*)&out };
        hipError_t e = hipLaunchCooperativeKernel(kfused, dim3((unsigned)nf), dim3(256),
                                                  kargs, 0u, stream);
        done = (e == hipSuccess);
    }

    if (!done) {
        // proven 4-kernel fallback
        k0_init     <<<3,  256, 0, stream>>>(tab);
        k1_stft     <<<nf, 256, 0, stream>>>(x_adv, x_ref, tab, psd_db, pd, fmaxs);
        k3_threshold<<<nf, 256, 0, stream>>>(tab, psd_db, pd, fmaxs, nf, floss);
        k4_final    <<<1,  256, 0, stream>>>(floss, nf, out);
    }
}